// Round 3
// baseline (1179.103 us; speedup 1.0000x reference)
//
#include <hip/hip_runtime.h>

#define NPROJ 180
#define DH 192
#define DW 384
#define VN 96
#define ZPER 8
#define ZCH (VN / ZPER)              // 12 z-chunks
#define TCOLS 20                     // |u-uc| <= 8.74 < 9 -> iu0=floor(uc)-9, taps [0,19]
#define TROWS 16                     // |v-vc| <= 6.71 < 7 -> iv0=floor(vc)-7, taps [0,15]
#define TENT (TCOLS * TROWS)         // 320 = 5*64: exact staging
#define PSTRIDE (DH * DW)
#define BSTRIDE (NPROJ * DH * DW)

typedef float v2f __attribute__((ext_vector_type(2)));

// r12: wave-private tiles, ZERO barriers. r11 showed both pipes <50% and
// stall-bound: VALU -35% gave no speedup. Each 8x8-xy wave (8z x 2batch per
// thread) stages its own 20x16 window (exact bounds: |u-uc|<=8.74<9 via
// |d_xy|*sqrt(1200^2+109.4^2)/682.8; |v-vc|<=6.71<7; same formula reproduces
// r7's proven 32x8 window) into a private double-buffered LDS region.
// Wave64 lockstep + per-wave in-order LDS -> no __syncthreads at all; the
// only waits are own-wave lgkmcnt/vmcnt. LDS = 4*2*320*8 = 20480 B exactly
// -> 8 blocks/CU = 32 waves resident (vs measured ~14 before). Anchors live
// in VGPRs (lane j holds proj j, packed iu0|iv0<<16; readlane -> SGPR base).
// Staging volume per block unchanged vs r11 (4x320=1280 entries/proj).
// Merge unchanged: quarters {0,1}->out, {2,3}->ws, exactly 2 order-free
// atomic addends per voxel per buffer; out += ws pass after.
template<int PQ, int NQ>
__global__ __launch_bounds__(256, 8) void cone_bp(
    const float* __restrict__ sino,   // [B, P, H, W]
    const float* __restrict__ mats,   // [P, 3, 4]
    float* __restrict__ out,          // [B, Z, Y, X]
    float* __restrict__ ws)           // quarters 2,3 (NQ=4 only)
{
    __shared__ v2f tile[4][2][TENT];  // 20480 B, wave-private regions

    const int tid  = threadIdx.x;
    const int lane = tid & 63;
    const int wv   = tid >> 6;

    const int lx = lane & 7;
    const int ly = lane >> 3;
    const int zi = blockIdx.z % 3;
    const int qt = blockIdx.z / 3;
    const int zch = zi * 4 + wv;      // 12 z-chunks, one per wave
    const int pbase = qt * PQ;

    const int x = blockIdx.x * 8 + lx;
    const int y = blockIdx.y * 8 + ly;
    const float xw = (float)x - 47.5f;
    const float yw = (float)y - 47.5f;
    const float zw0 = (float)(zch * ZPER) - 47.5f;

    // wave-tile center world coords (anchoring); half-extents 3.5 each
    const float xwc = (float)(blockIdx.x * 8) - 44.0f;
    const float ywc = (float)(blockIdx.y * 8) - 44.0f;
    const float zwc = (float)(zch * ZPER) - 44.0f;

    const float4* __restrict__ M = (const float4*)mats;

    // ---- per-lane anchor registers: lane j holds proj pbase+j packed ----
    // iu0 in [73,291], iv0 in [11,165]: both positive u16 -> pack safe.
    auto anchor = [&](int p) -> int {
        float4 a0 = M[p * 3 + 0];
        float4 a1 = M[p * 3 + 1];
        float4 a2 = M[p * 3 + 2];
        float unc = fmaf(a0.x, xwc, fmaf(a0.y, ywc, a0.w));
        float vnc = fmaf(a1.x, xwc, fmaf(a1.y, ywc, fmaf(a1.z, zwc, a1.w)));
        float wc  = fmaf(a2.x, xwc, fmaf(a2.y, ywc, a2.w));
        float rwc = __builtin_amdgcn_rcpf(wc);
        int iu0 = (int)floorf(unc * rwc) - 9;
        int iv0 = (int)floorf(vnc * rwc) - 7;
        return iu0 | (iv0 << 16);
    };
    int au = anchor(pbase + (lane < PQ ? lane : PQ - 1));
    int av = 0;
    if constexpr (PQ > 64)
        av = anchor(pbase + (lane + 64 < PQ ? lane + 64 : PQ - 1));

    auto getAnchor = [&](int idx, int& cu, int& cv) {
        int a;
        if constexpr (PQ > 64)
            a = (idx < 64) ? __builtin_amdgcn_readlane(au, idx)
                           : __builtin_amdgcn_readlane(av, idx - 64);
        else
            a = __builtin_amdgcn_readlane(au, idx);
        cu = a & 0xffff;
        cv = a >> 16;
    };

    // ---- staging map: loop-invariant element offsets ----
    int Vg[5];
#pragma unroll
    for (int k = 0; k < 5; ++k) {
        int li = lane + 64 * k;
        int row = li / TCOLS;
        int col = li - row * TCOLS;
        Vg[k] = row * DW + col;
    }

    v2f g[5];
    auto issue = [&](int p, int cu, int cv) {
        const float* __restrict__ base =
            sino + ((size_t)p * PSTRIDE + cv * DW + cu);
#pragma unroll
        for (int k = 0; k < 5; ++k) {
            g[k].x = base[Vg[k]];
            g[k].y = base[Vg[k] + BSTRIDE];
        }
    };

    v2f* const buf0 = tile[wv][0];
    v2f* const buf1 = tile[wv][1];
    auto store = [&](v2f* buf) {     // NO restrict: must order vs ds_reads
#pragma unroll
        for (int k = 0; k < 5; ++k)
            buf[lane + 64 * k] = g[k];
    };

    v2f acc[ZPER];
#pragma unroll
    for (int k = 0; k < ZPER; ++k) acc[k] = (v2f)(0.0f);

    auto sample = [&](int i, const v2f* buf, float nfu, float nfv) {
        const int p = pbase + i;
        float4 r0 = M[p * 3 + 0];
        float4 r1 = M[p * 3 + 1];
        float4 r2 = M[p * 3 + 2];
        float un  = fmaf(r0.x, xw, fmaf(r0.y, yw, r0.w));
        float vn0 = fmaf(r1.x, xw, fmaf(r1.y, yw, r1.w));
        float w   = fmaf(r2.x, xw, fmaf(r2.y, yw, r2.w));
        float rw  = __builtin_amdgcn_rcpf(w);
        float iw2 = rw * rw;                         // FDK 1/w^2
        float ul  = fmaf(un, rw, nfu);               // tile-local u (z-indep)
        float uf  = floorf(ul);
        float fu  = ul - uf;
        int   u0l = (int)uf;
        float vb  = fmaf(fmaf(r1.z, zw0, vn0), rw, nfv);
        float dv  = r1.z * rw;
#pragma unroll
        for (int gz = 0; gz < 2; ++gz) {
            int   o[4];
            float fv[4];
#pragma unroll
            for (int j = 0; j < 4; ++j) {
                float v  = fmaf(dv, (float)(4 * gz + j), vb);
                float vf = floorf(v);
                fv[j] = v - vf;
                o[j] = (int)vf * TCOLS + u0l;
            }
            v2f E00[4], E01[4], E10[4], E11[4];
#pragma unroll
            for (int j = 0; j < 4; ++j) {
                E00[j] = buf[o[j]];
                E01[j] = buf[o[j] + 1];
                E10[j] = buf[o[j] + TCOLS];
                E11[j] = buf[o[j] + TCOLS + 1];
            }
#pragma unroll
            for (int j = 0; j < 4; ++j) {
                v2f F0 = E00[j] + (E10[j] - E00[j]) * fv[j];
                v2f F1 = E01[j] + (E11[j] - E01[j]) * fv[j];
                v2f H  = F0 + (F1 - F0) * fu;
                acc[4 * gz + j] += H * iw2;
            }
        }
    };

    // ---- prologue: buf0 <- proj 0, g <- proj 1 ----
    int cu, cv;
    getAnchor(0, cu, cv);
    issue(pbase, cu, cv);
    float nfu0 = -(float)cu, nfv0 = -(float)cv;      // anchor of buf0's proj
    store(buf0);                                      // waits vmcnt, no barrier
    float nfuC = 0.0f, nfvC = 0.0f;                  // anchor of proj in g
    if (PQ > 1) {
        getAnchor(1, cu, cv);
        issue(pbase + 1, cu, cv);
        nfuC = -(float)cu; nfvC = -(float)cv;
    }

    for (int i = 0; i < PQ; i += 2) {
        // invariant: buf0 = proj i, g = proj i+1
        sample(i, buf0, nfu0, nfv0);
        if (i + 1 < PQ) {
            store(buf1);
            float nfu1 = nfuC, nfv1 = nfvC;
            if (i + 2 < PQ) {
                getAnchor(i + 2, cu, cv);
                issue(pbase + i + 2, cu, cv);
                nfuC = -(float)cu; nfvC = -(float)cv;
            }
            sample(i + 1, buf1, nfu1, nfv1);
            if (i + 2 < PQ) {
                store(buf0);
                nfu0 = nfuC; nfv0 = nfvC;
                if (i + 3 < PQ) {
                    getAnchor(i + 3, cu, cv);
                    issue(pbase + i + 3, cu, cv);
                    nfuC = -(float)cu; nfvC = -(float)cv;
                }
            }
        }
    }

    // ---- merge: exactly 2 atomic addends per voxel per buffer ----
    float* __restrict__ dst = (NQ == 4 && qt >= 2) ? ws : out;
    const int zbase = zch * ZPER;
#pragma unroll
    for (int k = 0; k < ZPER; ++k) {
        unsafeAtomicAdd(&dst[(((size_t)(zbase + k)) * VN + y) * VN + x],
                        acc[k].x);
        unsafeAtomicAdd(&dst[(((size_t)(VN + zbase + k)) * VN + y) * VN + x],
                        acc[k].y);
    }
}

// out += ws, float4-vectorized
__global__ __launch_bounds__(256) void add_ws(
    float4* __restrict__ out, const float4* __restrict__ ws, int n4)
{
    int i = blockIdx.x * 256 + threadIdx.x;
    if (i < n4) {
        float4 a = ws[i];
        float4 b = out[i];
        b.x += a.x; b.y += a.y; b.z += a.z; b.w += a.w;
        out[i] = b;
    }
}

extern "C" void kernel_launch(void* const* d_in, const int* in_sizes, int n_in,
                              void* d_out, int out_size, void* d_ws, size_t ws_size,
                              hipStream_t stream) {
    const float* sino = (const float*)d_in[0];   // [2,180,192,384,1] fp32
    const float* mats = (const float*)d_in[1];   // [180,3,4] fp32
    float* out = (float*)d_out;                  // [2,96,96,96,1] fp32
    float* wsf = (float*)d_ws;

    const size_t nvox = (size_t)2 * VN * VN * VN;           // 1769472
    // d_out is poisoned before every launch; atomic merge needs zeros
    hipMemsetAsync(out, 0, (size_t)out_size * sizeof(float), stream);

    if (ws_size >= nvox * sizeof(float)) {
        // 4 projection-quarters: grid 12 x 12 x (3 z-groups * 4 quarters)
        hipMemsetAsync(wsf, 0, nvox * sizeof(float), stream);
        dim3 grid(VN / 8, VN / 8, 3 * 4), block(256);
        hipLaunchKernelGGL((cone_bp<NPROJ / 4, 4>), grid, block, 0, stream,
                           sino, mats, out, wsf);
        int n4 = (int)(nvox / 4);
        hipLaunchKernelGGL(add_ws, dim3((n4 + 255) / 256), block, 0, stream,
                           (float4*)out, (const float4*)wsf, n4);
    } else {
        // fallback: 2 halves, no workspace needed
        dim3 grid(VN / 8, VN / 8, 3 * 2), block(256);
        hipLaunchKernelGGL((cone_bp<NPROJ / 2, 2>), grid, block, 0, stream,
                           sino, mats, out, (float*)nullptr);
    }
}

// Round 4
// 605.260 us; speedup vs baseline: 1.9481x; 1.9481x over previous
//
#include <hip/hip_runtime.h>

#define NPROJ 180
#define PHALF 90
#define DH 192
#define DW 384
#define VN 96
#define ZPER 4
#define TCOLS 65                     // u0l in [2,60] -> u0l+1 <= 64 in-window (r7-proven)
#define TROWS 14
#define TPAD 1024                    // 4x256 unguarded staging; tail rows benign in-detector
#define PSTRIDE (DH * DW)
#define BSTRIDE (NPROJ * DH * DW)

typedef float v2f __attribute__((ext_vector_type(2)));

// no-drain barrier: order LDS writes (lgkmcnt only) then sync. Global
// prefetch loads stay IN FLIGHT across the barrier -- __syncthreads()
// would drain vmcnt(0) here (the documented gfx950 barrier drain), which
// was r10/r11's per-projection ~300-900 cy stall.
#define BAR() asm volatile("s_waitcnt lgkmcnt(0)\n\ts_barrier" ::: "memory")

// r13 = r10 (186us champion: batch-interleaved 65-col tile, double buffer,
// 2-half split, 1 barrier/proj) + two fixes aimed at the barrier-drain stall:
//  1. raw s_barrier with lgkmcnt-only drain (BAR above): prefetch global
//     loads survive the barrier; ds_write of prefetch regs gets a counted
//     vmcnt wait (T4), not vmcnt(0).
//  2. depth-2 register prefetch (gA/gB): proj i+2's loads issue at proj i,
//     ~2 sample phases (>1000 cy) ahead of their ds_write -- covers HBM-miss
//     latency, not just L2-hit.
// Buffer-reuse safety is r10's proven invariant, unchanged: writer of
// tile[b] at proj i is two barriers after its last readers (proj i-2).
// r12's wave-private scheme is reverted entirely (FETCH exploded 8x: block
// drift thrashed XCD L2; block-cooperative staging restored).
__global__ __launch_bounds__(256, 6) void cone_bp(
    const float* __restrict__ sino,   // [B, P, H, W]
    const float* __restrict__ mats,   // [P, 3, 4]
    float* __restrict__ out)          // [B, Z, Y, X]
{
    __shared__ v2f tile[2][TPAD];     // 16 KB
    __shared__ int2 anch[PHALF];      // 720 B anchor table

    const int tid = threadIdx.x;
    // 8x8 per-wave lane map (r7-proven)
    const int x = blockIdx.x * 32 + ((tid & 7) | ((tid >> 6) << 3));
    const int y = blockIdx.y * 8 + ((tid >> 3) & 7);
    const int half = (blockIdx.z >= 24) ? 1 : 0;
    const int zc = blockIdx.z - 24 * half;
    const int pbase = half * PHALF;

    const float xw = (float)x - 47.5f;
    const float yw = (float)y - 47.5f;
    const float zw0 = (float)(zc * ZPER) - 47.5f;

    // block-center world coords (tile anchoring)
    const float xwc = (float)(blockIdx.x * 32) - 32.0f;
    const float ywc = (float)(blockIdx.y * 8) - 44.0f;
    const float zwc = (float)(zc * ZPER) - 46.0f;

    const float4* __restrict__ M = (const float4*)mats;

    // ---- anchor table: one projection per thread, once ----
    if (tid < PHALF) {
        int p = pbase + tid;
        float4 a0 = M[p * 3 + 0];
        float4 a1 = M[p * 3 + 1];
        float4 a2 = M[p * 3 + 2];
        float unc = fmaf(a0.x, xwc, fmaf(a0.y, ywc, a0.w));
        float vnc = fmaf(a1.x, xwc, fmaf(a1.y, ywc, fmaf(a1.z, zwc, a1.w)));
        float wc  = fmaf(a2.x, xwc, fmaf(a2.y, ywc, a2.w));
        float rwc = __builtin_amdgcn_rcpf(wc);
        anch[tid] = make_int2((int)floorf(unc * rwc) - 31,
                              (int)floorf(vnc * rwc) - 6);
    }

    // ---- staging map: loop-invariant BYTE offsets within a projection ----
    int VgB[4];
#pragma unroll
    for (int k = 0; k < 4; ++k) {
        int li = tid + 256 * k;
        int row = li / TCOLS;
        int col = li - row * TCOLS;
        VgB[k] = (row * DW + col) * 4;
    }

    __syncthreads();    // anchor table ready (once; full drain is fine here)

    auto issue = [&](int p, int cu, int cv, v2f* g) {
        const char* p0 = (const char*)(sino + (size_t)p * PSTRIDE + cv * DW + cu);
        const char* p1 = p0 + (size_t)BSTRIDE * 4;
#pragma unroll
        for (int k = 0; k < 4; ++k) {
            g[k].x = *(const float*)(p0 + VgB[k]);
            g[k].y = *(const float*)(p1 + VgB[k]);
        }
    };

    // ---- depth-2 prologue: gA <- proj 0, gB <- proj 1 ----
    int cu, cv;
    v2f gA[4], gB[4];
    {
        int2 a = anch[0];
        cu = __builtin_amdgcn_readfirstlane(a.x);
        cv = __builtin_amdgcn_readfirstlane(a.y);
    }
    issue(pbase, cu, cv, gA);
    float nfuA = -(float)cu, nfvA = -(float)cv;
    {
        int2 a = anch[1];
        cu = __builtin_amdgcn_readfirstlane(a.x);
        cv = __builtin_amdgcn_readfirstlane(a.y);
    }
    issue(pbase + 1, cu, cv, gB);
    float nfuB = -(float)cu, nfvB = -(float)cv;

    v2f acc[ZPER];
#pragma unroll
    for (int k = 0; k < ZPER; ++k) acc[k] = (v2f)(0.0f);

    auto sample = [&](int i, const v2f* buf, float nfu, float nfv) {
        const int p = pbase + i;
        float4 r0 = M[p * 3 + 0];
        float4 r1 = M[p * 3 + 1];
        float4 r2 = M[p * 3 + 2];
        float un  = fmaf(r0.x, xw, fmaf(r0.y, yw, r0.w));
        float vn0 = fmaf(r1.x, xw, fmaf(r1.y, yw, r1.w));
        float w   = fmaf(r2.x, xw, fmaf(r2.y, yw, r2.w));
        float rw  = __builtin_amdgcn_rcpf(w);
        float iw2 = rw * rw;                         // FDK 1/w^2
        float ul  = fmaf(un, rw, nfu);               // tile-local u (z-indep)
        float uf  = floorf(ul);
        float fu  = ul - uf;
        int   u0l = (int)uf;
        float vb  = fmaf(fmaf(r1.z, zw0, vn0), rw, nfv);
        float dv  = r1.z * rw;

        // phase 1: entry offsets + fv
        int   o[ZPER];
        float fv[ZPER];
#pragma unroll
        for (int k = 0; k < ZPER; ++k) {
            float v  = fmaf(dv, (float)k, vb);
            float vf = floorf(v);
            fv[k] = v - vf;
            o[k] = (int)vf * TCOLS + u0l;
        }
        // phase 2: all LDS reads (mergeable ds_read2_b64)
        v2f E00[ZPER], E01[ZPER], E10[ZPER], E11[ZPER];
#pragma unroll
        for (int k = 0; k < ZPER; ++k) {
            E00[k] = buf[o[k]];
            E01[k] = buf[o[k] + 1];
            E10[k] = buf[o[k] + TCOLS];
            E11[k] = buf[o[k] + TCOLS + 1];
        }
        // phase 3: fully packed bilinear + accumulate
#pragma unroll
        for (int k = 0; k < ZPER; ++k) {
            v2f F0 = E00[k] + (E10[k] - E00[k]) * fv[k];
            v2f F1 = E01[k] + (E11[k] - E01[k]) * fv[k];
            v2f H  = F0 + (F1 - F0) * fu;
            acc[k] += H * iw2;
        }
    };

    for (int i = 0; i < PHALF; i += 2) {
        // ---- proj i: tile[0] <- gA; prefetch i+2 -> gA ----
        {
#pragma unroll
            for (int k = 0; k < 4; ++k)          // counted vmcnt wait (gA only)
                tile[0][tid + 256 * k] = gA[k];
            const float su = nfuA, sv = nfvA;
            if (i + 2 < PHALF) {
                int2 a = anch[i + 2];
                cu = __builtin_amdgcn_readfirstlane(a.x);
                cv = __builtin_amdgcn_readfirstlane(a.y);
                issue(pbase + i + 2, cu, cv, gA);
                nfuA = -(float)cu; nfvA = -(float)cv;
            }
            BAR();                                // lgkm drain only; vmem flies
            sample(i, tile[0], su, sv);
        }
        // ---- proj i+1: tile[1] <- gB; prefetch i+3 -> gB ----
        {
#pragma unroll
            for (int k = 0; k < 4; ++k)
                tile[1][tid + 256 * k] = gB[k];
            const float su = nfuB, sv = nfvB;
            if (i + 3 < PHALF) {
                int2 a = anch[i + 3];
                cu = __builtin_amdgcn_readfirstlane(a.x);
                cv = __builtin_amdgcn_readfirstlane(a.y);
                issue(pbase + i + 3, cu, cv, gB);
                nfuB = -(float)cu; nfvB = -(float)cv;
            }
            BAR();
            sample(i + 1, tile[1], su, sv);
        }
    }

    // ---- merge: exactly 2 blocks per voxel -> order-independent fp32 add ----
    const int zbase = zc * ZPER;
#pragma unroll
    for (int k = 0; k < ZPER; ++k) {
        unsafeAtomicAdd(&out[(((size_t)(zbase + k)) * VN + y) * VN + x],
                        acc[k].x);
        unsafeAtomicAdd(&out[(((size_t)(VN + zbase + k)) * VN + y) * VN + x],
                        acc[k].y);
    }
}

extern "C" void kernel_launch(void* const* d_in, const int* in_sizes, int n_in,
                              void* d_out, int out_size, void* d_ws, size_t ws_size,
                              hipStream_t stream) {
    const float* sino = (const float*)d_in[0];   // [2,180,192,384,1] fp32
    const float* mats = (const float*)d_in[1];   // [180,3,4] fp32
    float* out = (float*)d_out;                  // [2,96,96,96,1] fp32

    // d_out is poisoned before every launch; atomic merge needs zeros
    hipMemsetAsync(out, 0, (size_t)out_size * sizeof(float), stream);

    // grid: 3 x-tiles, 12 y-tiles, 24 z-chunks x 2 projection halves
    dim3 grid(VN / 32, VN / 8, 48), block(256);
    hipLaunchKernelGGL(cone_bp, grid, block, 0, stream, sino, mats, out);
}